// Round 2
// baseline (238.634 us; speedup 1.0000x reference)
//
#include <hip/hip_runtime.h>
#include <math.h>

// Problem constants: B=128, C=48, H=W=64, p=32, N=4, D=49152
#define PLANE 4096            // 64*64
#define OUT0 25165824         // 128*48*64*64 (flat offset of logdet output)

typedef float fx4 __attribute__((ext_vector_type(4)));

// ws layout (floats):
#define WS_GT   0             // [2304]  GT[k*48+r] = G[r][k]
#define WS_PART 4096          // [128*2*4] score sums per (b, s): {s11,s12,s21,s22}

// Xc geometry: [s:2][c:48][row:8][jj padded to 18]
#define XSTR 18               // padded row stride (floats) -> staging-write conflicts ~2-way
#define KSTR 144              // 8*XSTR, per-channel (k) stride in floats

// ---------------- k0: GT[k*48+r] = sum_o Wq[o,r]*Wk[o,k] (3 pairs), LDS-staged W;
//                  also zeroes part[] (replaces the hipMemsetAsync dispatch) ----
__global__ __launch_bounds__(256) void g_kernel(const float* __restrict__ Wq1,
                                                const float* __restrict__ Wq2,
                                                const float* __restrict__ Wq3,
                                                const float* __restrict__ Wk1,
                                                const float* __restrict__ Wk2,
                                                const float* __restrict__ Wk3,
                                                float* __restrict__ GT,
                                                float* __restrict__ part) {
    __shared__ float Ws[6][2304];
    int tid = threadIdx.x;
    int idx = blockIdx.x * 256 + tid;     // grid 9*256 = 2304 exactly
    if (idx < 1024) part[idx] = 0.f;

    for (int i = tid; i < 2304; i += 256) {
        Ws[0][i] = Wq1[i];
        Ws[1][i] = Wk1[i];
        Ws[2][i] = Wq2[i];
        Ws[3][i] = Wk2[i];
        Ws[4][i] = Wq3[i];
        Ws[5][i] = Wk3[i];
    }
    __syncthreads();

    int k = idx / 48, r = idx % 48;       // GT[k*48+r] = G[r][k]
    float acc = 0.f;
#pragma unroll 8
    for (int o = 0; o < 48; ++o) {
        acc = fmaf(Ws[0][o * 48 + r], Ws[1][o * 48 + k], acc);
        acc = fmaf(Ws[2][o * 48 + r], Ws[3][o * 48 + k], acc);
        acc = fmaf(Ws[4][o * 48 + r], Ws[5][o * 48 + k], acc);
    }
    GT[idx] = acc;
}

// ---------------- k1: scores via r-split quadratic forms, LDS-staged x ----------
// grid 1024 = b(128) x g(8 row-groups); block 256 = [s:2][ilg:2][jj:16][rc:4].
// Each thread handles TWO pixel rows (il0, il1): 3 broadcast ds_read_b128 (G) now
// amortize over 96 FMAs (was 24) -> 2.7x fewer LDS issue slots per FLOP.
__global__ __launch_bounds__(256) void score_kernel(const float* __restrict__ x,
                                                    const float* __restrict__ GT,
                                                    float* __restrict__ part) {
    __shared__ float Gs[2304];
    __shared__ float Xc[2 * 48 * KSTR];   // 55296 B
    __shared__ float red[4][8];
    int tid = threadIdx.x;
    int bid = blockIdx.x;
    int g = bid & 7;
    int b = bid >> 3;

    for (int i = tid; i < 2304; i += 256) Gs[i] = GT[i];

    // ---- stage: 6144 fx4 = full rows h=4g..4g+3 (top) and 4g+32..4g+35 (bottom),
    //      parity-compacted: Xc[s][c][row][jj] keeps only masked-parity columns.
    const float* xb = x + (size_t)b * (48 * PLANE);
#pragma unroll 4
    for (int t = 0; t < 24; ++t) {
        int l = t * 256 + tid;            // 0..6143
        int c = l >> 7;                   // 0..47
        int row = (l >> 4) & 7;           // 0-3 top, 4-7 bottom
        int w4 = l & 15;                  // fx4 index within the 64-col row
        int h = 4 * g + row + ((row >= 4) ? 28 : 0);
        fx4 d = *(const fx4*)(xb + c * PLANE + h * 64 + w4 * 4);
        int s = w4 >> 3;                  // left half -> s=0 (even cols), right -> s=1 (odd)
        int w4p = w4 & 7;
        float2 pr;                        // the two parity-s elements of this fx4
        pr.x = s ? d[1] : d[0];
        pr.y = s ? d[3] : d[2];
        *(float2*)(&Xc[(s * 48 + c) * KSTR + row * XSTR + 2 * w4p]) = pr;
    }
    __syncthreads();

    // ---- compute: thread = (s, ilg, jj, rc); rows il0=2*ilg, il1=il0+1
    int rc = tid & 3;                     // r-chunk: rows rc*12 .. rc*12+11 of G
    int jj = (tid >> 2) & 15;             // masked column index
    int ilg = (tid >> 6) & 1;
    int s = tid >> 7;
    int il0 = ilg * 2;

    const float* X0 = &Xc[s * 48 * KSTR + il0 * XSTR + jj];
    // t0 = X0[k*KSTR]          (top row il0)     v0 = X0[k*KSTR + 4*XSTR]
    // t1 = X0[k*KSTR + XSTR]   (top row il0+1)   v1 = X0[k*KSTR + 5*XSTR]

    float u1a[12], u2a[12], u1b[12], u2b[12];
    float a1a[12], a2a[12], a1b[12], a2b[12];
#pragma unroll
    for (int j = 0; j < 12; ++j) {
        u1a[j] = 0.f; u2a[j] = 0.f; u1b[j] = 0.f; u2b[j] = 0.f;
        a1a[j] = 0.f; a2a[j] = 0.f; a1b[j] = 0.f; a2b[j] = 0.f;
    }

    const fx4* gb = (const fx4*)(Gs + rc * 12);   // 48B-aligned

#pragma unroll
    for (int k = 0; k < 48; ++k) {
        float t0 = X0[k * KSTR];
        float t1 = X0[k * KSTR + XSTR];
        float v0 = X0[k * KSTR + 4 * XSTR];
        float v1 = X0[k * KSTR + 5 * XSTR];
        fx4 gA = gb[k * 12 + 0];          // Gs[k*48 + rc*12 + 0..3]
        fx4 gB = gb[k * 12 + 1];
        fx4 gC = gb[k * 12 + 2];
#pragma unroll
        for (int j = 0; j < 4; ++j) {
            u1a[j]     = fmaf(gA[j], t0, u1a[j]);
            u2a[j]     = fmaf(gA[j], v0, u2a[j]);
            u1b[j]     = fmaf(gA[j], t1, u1b[j]);
            u2b[j]     = fmaf(gA[j], v1, u2b[j]);
            u1a[j + 4] = fmaf(gB[j], t0, u1a[j + 4]);
            u2a[j + 4] = fmaf(gB[j], v0, u2a[j + 4]);
            u1b[j + 4] = fmaf(gB[j], t1, u1b[j + 4]);
            u2b[j + 4] = fmaf(gB[j], v1, u2b[j + 4]);
            u1a[j + 8] = fmaf(gC[j], t0, u1a[j + 8]);
            u2a[j + 8] = fmaf(gC[j], v0, u2a[j + 8]);
            u1b[j + 8] = fmaf(gC[j], t1, u1b[j + 8]);
            u2b[j + 8] = fmaf(gC[j], v1, u2b[j + 8]);
        }
        // capture t/v into this thread's r-chunk registers when k is in-chunk
        const int q = k / 12, j0 = k % 12;
        bool m = (rc == q);
        a1a[j0] = m ? t0 : a1a[j0];
        a2a[j0] = m ? v0 : a2a[j0];
        a1b[j0] = m ? t1 : a1b[j0];
        a2b[j0] = m ? v1 : a2b[j0];
    }

    float sm[8];
#pragma unroll
    for (int q = 0; q < 8; ++q) sm[q] = 0.f;
#pragma unroll
    for (int j = 0; j < 12; ++j) {
        sm[0] = fmaf(a1a[j], u1a[j], sm[0]);   // s11 (top,top) row il0
        sm[1] = fmaf(a1a[j], u2a[j], sm[1]);   // s12 (top,bot)
        sm[2] = fmaf(a2a[j], u1a[j], sm[2]);   // s21 (bot,top)
        sm[3] = fmaf(a2a[j], u2a[j], sm[3]);   // s22 (bot,bot)
        sm[4] = fmaf(a1b[j], u1b[j], sm[4]);   // same, row il1
        sm[5] = fmaf(a1b[j], u2b[j], sm[5]);
        sm[6] = fmaf(a2b[j], u1b[j], sm[6]);
        sm[7] = fmaf(a2b[j], u2b[j], sm[7]);
    }

    // full-wave butterfly: sums over the 4 r-chunks AND the wave's 16 jj columns
#pragma unroll
    for (int off = 1; off < 64; off <<= 1) {
#pragma unroll
        for (int q = 0; q < 8; ++q) sm[q] += __shfl_xor(sm[q], off, 64);
    }
    int wv = tid >> 6;                    // wave = (s, ilg)
    if ((tid & 63) == 0) {
#pragma unroll
        for (int q = 0; q < 8; ++q) red[wv][q] = sm[q];
    }
    __syncthreads();
    if (tid < 8) {
        int so = tid >> 2, q = tid & 3;
        float tot = red[so * 2][q] + red[so * 2][q + 4] +
                    red[so * 2 + 1][q] + red[so * 2 + 1][q + 4];
        atomicAdd(&part[(b * 2 + so) * 4 + q], tot);
    }
}

// ---------------- k2: streaming output + fused attn/softmax/logdet ----------------
__global__ __launch_bounds__(256) void out_kernel(const float* __restrict__ x,
                                                  const float* __restrict__ part,
                                                  const float* __restrict__ logdet_in,
                                                  const float* __restrict__ off_p,
                                                  const float* __restrict__ off2_p,
                                                  float* __restrict__ out,
                                                  float* __restrict__ out_logdet) {
    int bc = blockIdx.x;            // 128*48
    int b = bc / 48;

    const float inv_scale = 4.5105361e-3f;   // 1/sqrt(49152)
    float off = off_p[0];
    float c2o = off2_p[0];
    float ld = 0.f;
    float Ad[4], Ao[4];
#pragma unroll
    for (int s = 0; s < 2; ++s) {
        int base = (b * 2 + s) * 4;
        float stt = part[base + 0] * inv_scale;
        float stb = part[base + 1] * inv_scale;
        float sbt = part[base + 2] * inv_scale;
        float sbb = part[base + 3] * inv_scale;

        float m0 = fmaxf(fmaxf(stt, stb), 0.f);
        float e00 = expf(stt - m0), e01 = expf(stb - m0), ez0 = expf(-m0);
        float d0 = e00 + e01 + 2.f * ez0;
        float ptt = e00 / d0, ptb = e01 / d0;
        float m1 = fmaxf(fmaxf(sbt, sbb), 0.f);
        float e10 = expf(sbt - m1), e11 = expf(sbb - m1), ez1 = expf(-m1);
        float d1 = e10 + e11 + 2.f * ez1;
        float pbt = e10 / d1, pbb = e11 / d1;

        float adt = ptt + c2o + off;
        float aot = ptb + c2o;
        float adb = pbb + c2o + off;
        float aob = pbt + c2o;
        Ad[s] = adt; Ao[s] = aot; Ad[s + 2] = adb; Ao[s + 2] = aob;
        float det = adt * adb - aot * aob;
        ld += logf(fabsf(det));
    }
    if ((bc - b * 48) == 0 && threadIdx.x == 0) {
        out_logdet[b] = logdet_in[b] + ld * 24576.0f;
    }

    const fx4* xb4 = (const fx4*)(x + (size_t)bc * PLANE);
    fx4* ob4 = (fx4*)(out + (size_t)bc * PLANE);
    int tid = threadIdx.x;
#pragma unroll
    for (int it = 0; it < 2; ++it) {
        int f = it * 256 + tid;       // 0..511
        int h = f >> 4;               // 0..31
        int w4 = f & 15;
        fx4 xt = __builtin_nontemporal_load(&xb4[h * 16 + w4]);
        fx4 xv = __builtin_nontemporal_load(&xb4[(h + 32) * 16 + w4]);
        int wb = w4 >> 3;
        float Adt = wb ? Ad[1] : Ad[0];
        float Aot = wb ? Ao[1] : Ao[0];
        float Adb = wb ? Ad[3] : Ad[2];
        float Aob = wb ? Ao[3] : Ao[2];

        fx4 rt, rv;
#pragma unroll
        for (int q = 0; q < 4; ++q) {
            int e = (wb + q) & 1;
            float t = xt[q], v = xv[q];
            float mt = fmaf(Adt, t, Aot * v);
            float mv = fmaf(Adb, v, Aob * t);
            rt[q] = e ? mt : t;
            rv[q] = e ? mv : v;
        }
        __builtin_nontemporal_store(rt, &ob4[h * 16 + w4]);
        __builtin_nontemporal_store(rv, &ob4[(h + 32) * 16 + w4]);
    }
}

extern "C" void kernel_launch(void* const* d_in, const int* in_sizes, int n_in,
                              void* d_out, int out_size, void* d_ws, size_t ws_size,
                              hipStream_t stream) {
    const float* x      = (const float*)d_in[0];
    const float* logdet = (const float*)d_in[1];
    const float* Wq1    = (const float*)d_in[2];
    const float* Wq2    = (const float*)d_in[3];
    const float* Wq3    = (const float*)d_in[4];
    const float* Wk1    = (const float*)d_in[5];
    const float* Wk2    = (const float*)d_in[6];
    const float* Wk3    = (const float*)d_in[7];
    const float* off    = (const float*)d_in[8];
    const float* off2   = (const float*)d_in[9];
    // d_in[10] (offset3) is a uniform pre-softmax shift -> cancels; unused.

    float* out = (float*)d_out;
    float* ws  = (float*)d_ws;
    float* GT   = ws + WS_GT;
    float* part = ws + WS_PART;

    g_kernel<<<9, 256, 0, stream>>>(Wq1, Wq2, Wq3, Wk1, Wk2, Wk3, GT, part);
    score_kernel<<<1024, 256, 0, stream>>>(x, GT, part);
    out_kernel<<<6144, 256, 0, stream>>>(x, part, logdet, off, off2, out, out + OUT0);
}

// Round 3
// 220.901 us; speedup vs baseline: 1.0803x; 1.0803x over previous
//
#include <hip/hip_runtime.h>
#include <math.h>

// Problem constants: B=128, C=48, H=W=64, p=32, N=4, D=49152
#define PLANE 4096            // 64*64
#define OUT0 25165824         // 128*48*64*64 (flat offset of logdet output)

typedef float fx4 __attribute__((ext_vector_type(4)));

// ws layout (floats):
#define WS_GT   0             // [2304]  GT[k*48+r] = G[r][k]
#define WS_PART 4096          // [128*2*4] score sums per (b, s): {s11,s12,s21,s22}

// ---------------- k0: GT[k*48+r] = sum_o Wq[o,r]*Wk[o,k] (3 pairs), LDS-staged W;
//                  also zeroes part[] (replaces the hipMemsetAsync dispatch) ----
__global__ __launch_bounds__(256) void g_kernel(const float* __restrict__ Wq1,
                                                const float* __restrict__ Wq2,
                                                const float* __restrict__ Wq3,
                                                const float* __restrict__ Wk1,
                                                const float* __restrict__ Wk2,
                                                const float* __restrict__ Wk3,
                                                float* __restrict__ GT,
                                                float* __restrict__ part) {
    __shared__ float Ws[6][2304];
    int tid = threadIdx.x;
    int idx = blockIdx.x * 256 + tid;     // grid 9*256 = 2304 exactly
    if (idx < 1024) part[idx] = 0.f;

    for (int i = tid; i < 2304; i += 256) {
        Ws[0][i] = Wq1[i];
        Ws[1][i] = Wk1[i];
        Ws[2][i] = Wq2[i];
        Ws[3][i] = Wk2[i];
        Ws[4][i] = Wq3[i];
        Ws[5][i] = Wk3[i];
    }
    __syncthreads();

    int k = idx / 48, r = idx % 48;       // GT[k*48+r] = G[r][k]
    float acc = 0.f;
#pragma unroll 8
    for (int o = 0; o < 48; ++o) {
        acc = fmaf(Ws[0][o * 48 + r], Ws[1][o * 48 + k], acc);
        acc = fmaf(Ws[2][o * 48 + r], Ws[3][o * 48 + k], acc);
        acc = fmaf(Ws[4][o * 48 + r], Ws[5][o * 48 + k], acc);
    }
    GT[idx] = acc;
}

// ---------------- k1: scores via r-split quadratic forms ----------
// grid 2048 = b(128) x g(16 groups of 2 i-rows); block 256 = 4 waves.
// Wave w owns r-chunk rc=w (WAVE-UNIFORM -> G loads become scalar s_load from
// L2, ZERO LDS-pipe cost). Lanes = (s:2)x(il:2)x(jj:16) = 64 pixel-pairs.
// LDS per wave per k: just 2 conflict-free b32 reads (t, v).
__global__ __launch_bounds__(256, 5) void score_kernel(const float* __restrict__ x,
                                                       const float* __restrict__ GT,
                                                       float* __restrict__ part) {
    __shared__ float Xc[2 * 48 * 64];     // [s][c][row:4][jj:16] = 24 KB, unpadded
    __shared__ float red[4][2][4];
    int tid = threadIdx.x;
    int bid = blockIdx.x;
    int g = bid & 15;                     // 16 groups of 2 i-rows
    int b = bid >> 4;

    // ---- stage: 48c x 4 h-rows (2 top + 2 bottom) x 64 cols, parity-compacted.
    // Each wave: one channel, two 512B contiguous chunks -> clean coalescing.
    const float* xb = x + (size_t)b * (48 * PLANE);
#pragma unroll
    for (int t = 0; t < 12; ++t) {
        int l = t * 256 + tid;            // 0..3071
        int c = l >> 6;                   // 0..47
        int row = (l >> 4) & 3;           // 0,1 top; 2,3 bottom
        int w4 = l & 15;                  // fx4 index within the 64-col row
        int h = 2 * g + (row & 1) + ((row >> 1) << 5);
        fx4 d = *(const fx4*)(xb + c * PLANE + h * 64 + w4 * 4);
        int s = w4 >> 3;                  // left half -> s=0 (even cols), right -> s=1 (odd)
        int w4p = w4 & 7;
        float2 pr;                        // the two parity-s elements of this fx4
        pr.x = s ? d[1] : d[0];
        pr.y = s ? d[3] : d[2];
        *(float2*)(&Xc[(s * 48 + c) * 64 + row * 16 + 2 * w4p]) = pr;
    }
    __syncthreads();

    // ---- compute: wave = r-chunk, lane = (s, il, jj)
    int rc = __builtin_amdgcn_readfirstlane(tid >> 6);   // wave-uniform r-chunk
    int lane = tid & 63;
    int s = lane >> 5;
    int il = (lane >> 4) & 1;
    int jj = lane & 15;

    const float* X0 = &Xc[(s * 48) * 64 + il * 16 + jj];
    // t = X0[k*64] (top), v = X0[k*64 + 32] (bottom); banks: 2-way across wave = free.

    const float* __restrict__ gbase = GT + rc * 12;      // uniform -> s_load path

    float u1[12], u2[12], a1[12], a2[12];
#pragma unroll
    for (int j = 0; j < 12; ++j) { u1[j] = 0.f; u2[j] = 0.f; a1[j] = 0.f; a2[j] = 0.f; }

#pragma unroll
    for (int k = 0; k < 48; ++k) {
        float t = X0[k * 64];
        float v = X0[k * 64 + 32];
        fx4 gA = *(const fx4*)(gbase + k * 48);       // G[rc*12+0..3][k]
        fx4 gB = *(const fx4*)(gbase + k * 48 + 4);
        fx4 gC = *(const fx4*)(gbase + k * 48 + 8);
#pragma unroll
        for (int j = 0; j < 4; ++j) {
            u1[j]     = fmaf(gA[j], t, u1[j]);
            u2[j]     = fmaf(gA[j], v, u2[j]);
            u1[j + 4] = fmaf(gB[j], t, u1[j + 4]);
            u2[j + 4] = fmaf(gB[j], v, u2[j + 4]);
            u1[j + 8] = fmaf(gC[j], t, u1[j + 8]);
            u2[j + 8] = fmaf(gC[j], v, u2[j + 8]);
        }
        // capture t/v into this wave's r-chunk registers when k is in-chunk
        const int q = k / 12, j0 = k % 12;
        bool m = (rc == q);               // wave-uniform select
        a1[j0] = m ? t : a1[j0];
        a2[j0] = m ? v : a2[j0];
    }

    float s11 = 0.f, s12 = 0.f, s21 = 0.f, s22 = 0.f;
#pragma unroll
    for (int j = 0; j < 12; ++j) {
        s11 = fmaf(a1[j], u1[j], s11);    // (top,top)
        s12 = fmaf(a1[j], u2[j], s12);    // (top,bot)
        s21 = fmaf(a2[j], u1[j], s21);    // (bot,top)
        s22 = fmaf(a2[j], u2[j], s22);    // (bot,bot)
    }

    // butterfly over lane bits 0..4 (jj, il) — keeps the two s-halves separate
#pragma unroll
    for (int off = 1; off < 32; off <<= 1) {
        s11 += __shfl_xor(s11, off, 64);
        s12 += __shfl_xor(s12, off, 64);
        s21 += __shfl_xor(s21, off, 64);
        s22 += __shfl_xor(s22, off, 64);
    }
    if ((lane & 31) == 0) {               // lane 0 -> s=0 sums, lane 32 -> s=1 sums
        red[rc][s][0] = s11; red[rc][s][1] = s12; red[rc][s][2] = s21; red[rc][s][3] = s22;
    }
    __syncthreads();
    if (tid < 8) {
        int so = tid >> 2, q = tid & 3;
        float tot = red[0][so][q] + red[1][so][q] + red[2][so][q] + red[3][so][q];
        atomicAdd(&part[(b * 2 + so) * 4 + q], tot);
    }
}

// ---------------- k2: streaming output + fused attn/softmax/logdet ----------------
__global__ __launch_bounds__(256) void out_kernel(const float* __restrict__ x,
                                                  const float* __restrict__ part,
                                                  const float* __restrict__ logdet_in,
                                                  const float* __restrict__ off_p,
                                                  const float* __restrict__ off2_p,
                                                  float* __restrict__ out,
                                                  float* __restrict__ out_logdet) {
    int bc = blockIdx.x;            // 128*48
    int b = bc / 48;

    const float inv_scale = 4.5105361e-3f;   // 1/sqrt(49152)
    float off = off_p[0];
    float c2o = off2_p[0];
    float ld = 0.f;
    float Ad[4], Ao[4];
#pragma unroll
    for (int s = 0; s < 2; ++s) {
        int base = (b * 2 + s) * 4;
        float stt = part[base + 0] * inv_scale;
        float stb = part[base + 1] * inv_scale;
        float sbt = part[base + 2] * inv_scale;
        float sbb = part[base + 3] * inv_scale;

        float m0 = fmaxf(fmaxf(stt, stb), 0.f);
        float e00 = expf(stt - m0), e01 = expf(stb - m0), ez0 = expf(-m0);
        float d0 = e00 + e01 + 2.f * ez0;
        float ptt = e00 / d0, ptb = e01 / d0;
        float m1 = fmaxf(fmaxf(sbt, sbb), 0.f);
        float e10 = expf(sbt - m1), e11 = expf(sbb - m1), ez1 = expf(-m1);
        float d1 = e10 + e11 + 2.f * ez1;
        float pbt = e10 / d1, pbb = e11 / d1;

        float adt = ptt + c2o + off;
        float aot = ptb + c2o;
        float adb = pbb + c2o + off;
        float aob = pbt + c2o;
        Ad[s] = adt; Ao[s] = aot; Ad[s + 2] = adb; Ao[s + 2] = aob;
        float det = adt * adb - aot * aob;
        ld += logf(fabsf(det));
    }
    if ((bc - b * 48) == 0 && threadIdx.x == 0) {
        out_logdet[b] = logdet_in[b] + ld * 24576.0f;
    }

    const fx4* xb4 = (const fx4*)(x + (size_t)bc * PLANE);
    fx4* ob4 = (fx4*)(out + (size_t)bc * PLANE);
    int tid = threadIdx.x;
#pragma unroll
    for (int it = 0; it < 2; ++it) {
        int f = it * 256 + tid;       // 0..511
        int h = f >> 4;               // 0..31
        int w4 = f & 15;
        fx4 xt = __builtin_nontemporal_load(&xb4[h * 16 + w4]);
        fx4 xv = __builtin_nontemporal_load(&xb4[(h + 32) * 16 + w4]);
        int wb = w4 >> 3;
        float Adt = wb ? Ad[1] : Ad[0];
        float Aot = wb ? Ao[1] : Ao[0];
        float Adb = wb ? Ad[3] : Ad[2];
        float Aob = wb ? Ao[3] : Ao[2];

        fx4 rt, rv;
#pragma unroll
        for (int q = 0; q < 4; ++q) {
            int e = (wb + q) & 1;
            float t = xt[q], v = xv[q];
            float mt = fmaf(Adt, t, Aot * v);
            float mv = fmaf(Adb, v, Aob * t);
            rt[q] = e ? mt : t;
            rv[q] = e ? mv : v;
        }
        __builtin_nontemporal_store(rt, &ob4[h * 16 + w4]);
        __builtin_nontemporal_store(rv, &ob4[(h + 32) * 16 + w4]);
    }
}

extern "C" void kernel_launch(void* const* d_in, const int* in_sizes, int n_in,
                              void* d_out, int out_size, void* d_ws, size_t ws_size,
                              hipStream_t stream) {
    const float* x      = (const float*)d_in[0];
    const float* logdet = (const float*)d_in[1];
    const float* Wq1    = (const float*)d_in[2];
    const float* Wq2    = (const float*)d_in[3];
    const float* Wq3    = (const float*)d_in[4];
    const float* Wk1    = (const float*)d_in[5];
    const float* Wk2    = (const float*)d_in[6];
    const float* Wk3    = (const float*)d_in[7];
    const float* off    = (const float*)d_in[8];
    const float* off2   = (const float*)d_in[9];
    // d_in[10] (offset3) is a uniform pre-softmax shift -> cancels; unused.

    float* out = (float*)d_out;
    float* ws  = (float*)d_ws;
    float* GT   = ws + WS_GT;
    float* part = ws + WS_PART;

    g_kernel<<<9, 256, 0, stream>>>(Wq1, Wq2, Wq3, Wk1, Wk2, Wk3, GT, part);
    score_kernel<<<2048, 256, 0, stream>>>(x, GT, part);
    out_kernel<<<6144, 256, 0, stream>>>(x, part, logdet, off, off2, out, out + OUT0);
}